// Round 2
// baseline (659.518 us; speedup 1.0000x reference)
//
#include <hip/hip_runtime.h>
#include <cstdint>
#include <cstddef>

// ---------------------------------------------------------------------------
// GCN 2-layer: out = GCNConv2( relu( GCNConv1(x) ) )
//   1. Build degree + CSR (grouped by dst) once per call; reused by both layers.
//   2. h1 = x @ W1            (LDS-staged tile GEMM, no spills)
//   3. g1 = relu(prop(h1)+b1) (pull-style gather, 4-way unrolled, no float atomics)
//   4. h2 = g1 @ W2
//   5. out = prop(h2) + b2
// Edge dtype (int32 vs int64) detected on-device via high words.
// ---------------------------------------------------------------------------

__global__ void k_init(int* __restrict__ cnt, int N, int* __restrict__ flag) {
  int i = blockIdx.x * blockDim.x + threadIdx.x;
  if (i < N) cnt[i] = 0;
  if (i == 0) *flag = 1;  // assume int64 until proven otherwise
}

__global__ void k_detect(const int* __restrict__ e32, int twoE, int* __restrict__ flag) {
  int i = blockIdx.x * blockDim.x + threadIdx.x;
  if (i < 1024) {
    int idx = 2 * i + 1;  // odd int32 slots = high words if buffer is int64
    if (idx < twoE && e32[idx] != 0) atomicAnd(flag, 0);  // int32 data
  }
}

__device__ __forceinline__ int load_edge(const int* e32, int idx, int is64) {
  if (is64) return (int)((const long long*)e32)[idx];
  return e32[idx];
}

__global__ void k_hist(const int* __restrict__ e32, int E, int* __restrict__ cnt,
                       const int* __restrict__ flag) {
  int i = blockIdx.x * blockDim.x + threadIdx.x;
  if (i >= E) return;
  int is64 = *flag;
  int d = load_edge(e32, E + i, is64);
  atomicAdd(&cnt[d], 1);
}

__global__ void k_dinv(const int* __restrict__ cnt, float* __restrict__ dinv, int N) {
  int i = blockIdx.x * blockDim.x + threadIdx.x;
  if (i < N) dinv[i] = rsqrtf((float)cnt[i] + 1.0f);  // +1 = self-loop
}

// ---- exclusive scan of cnt -> rowptr (3-pass, 1024 elems/block) ----
__global__ void k_scan1(const int* __restrict__ cnt, int N, int* __restrict__ rowptr,
                        int* __restrict__ partial) {
  __shared__ int sh[256];
  const int t = threadIdx.x;
  const int base = blockIdx.x * 1024 + t * 4;
  int v0 = (base + 0 < N) ? cnt[base + 0] : 0;
  int v1 = (base + 1 < N) ? cnt[base + 1] : 0;
  int v2 = (base + 2 < N) ? cnt[base + 2] : 0;
  int v3 = (base + 3 < N) ? cnt[base + 3] : 0;
  int s = v0 + v1 + v2 + v3;
  sh[t] = s;
  __syncthreads();
  for (int off = 1; off < 256; off <<= 1) {
    int add = (t >= off) ? sh[t - off] : 0;
    __syncthreads();
    sh[t] += add;
    __syncthreads();
  }
  int excl = sh[t] - s;
  if (base + 0 < N) rowptr[base + 0] = excl;
  if (base + 1 < N) rowptr[base + 1] = excl + v0;
  if (base + 2 < N) rowptr[base + 2] = excl + v0 + v1;
  if (base + 3 < N) rowptr[base + 3] = excl + v0 + v1 + v2;
  if (t == 255) partial[blockIdx.x] = sh[255];
}

__global__ void k_scan2(int* __restrict__ partial, int NB) {
  __shared__ int sh[256];
  int t = threadIdx.x;
  int v = (t < NB) ? partial[t] : 0;
  sh[t] = v;
  __syncthreads();
  for (int off = 1; off < 256; off <<= 1) {
    int add = (t >= off) ? sh[t - off] : 0;
    __syncthreads();
    sh[t] += add;
    __syncthreads();
  }
  if (t < NB) partial[t] = sh[t] - v;  // exclusive
}

__global__ void k_scan3(int* __restrict__ rowptr, int* __restrict__ cursor,
                        const int* __restrict__ partial, int N, int E) {
  int i = blockIdx.x * blockDim.x + threadIdx.x;
  if (i < N) {
    int r = rowptr[i] + partial[i >> 10];
    rowptr[i] = r;
    cursor[i] = r;
  }
  if (i == 0) rowptr[N] = E;
}

__global__ void k_fill(const int* __restrict__ e32, int E, const float* __restrict__ dinv,
                       int* __restrict__ cursor, int2* __restrict__ rec,
                       const int* __restrict__ flag) {
  int i = blockIdx.x * blockDim.x + threadIdx.x;
  if (i >= E) return;
  int is64 = *flag;
  int s = load_edge(e32, i, is64);
  int d = load_edge(e32, E + i, is64);
  int pos = atomicAdd(&cursor[d], 1);
  float w = dinv[s] * dinv[d];
  rec[pos] = make_int2(s, __float_as_int(w));
}

// ---- dense transform H[N][COUT] = X[N][CIN] @ W[CIN][COUT] ----
// 64 rows per 256-thread block. X tile staged in LDS (contiguous, coalesced).
// Compute reads Xs via b128 broadcast; W rows from global (L1-resident).
template <int CIN, int COUT>
__global__ void k_gemm(const float* __restrict__ X, const float* __restrict__ W,
                       float* __restrict__ H, int N) {
  constexpr int ROWS = 64;
  constexpr int R4 = CIN / 4;  // float4 per row
  __shared__ float4 Xs[ROWS * R4];
  const int t = threadIdx.x;
  const int rowbase = blockIdx.x * ROWS;
  const float4* X4 = (const float4*)X;
#pragma unroll
  for (int i = t; i < ROWS * R4; i += 256) {
    int r = i / R4;
    int k4 = i % R4;
    int gr = rowbase + r;
    if (gr > N - 1) gr = N - 1;  // tail clamp (dup reads, harmless)
    Xs[i] = X4[(size_t)gr * R4 + k4];
  }
  __syncthreads();

  constexpr int GROUPS = 256 / COUT;
  constexpr int RPG = ROWS / GROUPS;
  const int c = t % COUT;
  const int g = t / COUT;
  float acc[RPG];
#pragma unroll
  for (int r = 0; r < RPG; ++r) acc[r] = 0.f;
  for (int k4 = 0; k4 < R4; ++k4) {  // no unroll: keep VGPR demand low
    float w0 = W[(k4 * 4 + 0) * COUT + c];
    float w1 = W[(k4 * 4 + 1) * COUT + c];
    float w2 = W[(k4 * 4 + 2) * COUT + c];
    float w3 = W[(k4 * 4 + 3) * COUT + c];
#pragma unroll
    for (int r = 0; r < RPG; ++r) {
      float4 xv = Xs[(g * RPG + r) * R4 + k4];  // wave-broadcast LDS read
      acc[r] = fmaf(xv.x, w0, acc[r]);
      acc[r] = fmaf(xv.y, w1, acc[r]);
      acc[r] = fmaf(xv.z, w2, acc[r]);
      acc[r] = fmaf(xv.w, w3, acc[r]);
    }
  }
#pragma unroll
  for (int r = 0; r < RPG; ++r) {
    int n = rowbase + g * RPG + r;
    if (n < N) H[(size_t)n * COUT + c] = acc[r];
  }
}

// ---- pull-style propagation: one wave per destination node ----
// 4-way unrolled edge loop: 4 independent accumulators -> 4 row-gathers
// (1 KB) in flight per wave, breaking the fmaf dependency chain.
template <int C, bool RELU>
__global__ void k_prop(const float* __restrict__ H, const int2* __restrict__ rec,
                       const int* __restrict__ rowptr, const float* __restrict__ dinv,
                       const float* __restrict__ bias, float* __restrict__ out, int N) {
  const int gid = blockIdx.x * blockDim.x + threadIdx.x;
  const int n = gid >> 6;
  const int lane = threadIdx.x & 63;
  if (n >= N) return;
  const int c = lane & (C - 1);
  const float di = dinv[n];
  const int beg = rowptr[n];
  const int end = rowptr[n + 1];
  float a0, a1 = 0.f, a2 = 0.f, a3 = 0.f;
  if (C == 64) {
    a0 = H[(size_t)n * C + c] * (di * di);  // self-loop term
    int e = beg;
    for (; e + 4 <= end; e += 4) {
      int2 r0 = rec[e + 0];
      int2 r1 = rec[e + 1];
      int2 r2 = rec[e + 2];
      int2 r3 = rec[e + 3];
      a0 = fmaf(__int_as_float(r0.y), H[(size_t)r0.x * C + c], a0);
      a1 = fmaf(__int_as_float(r1.y), H[(size_t)r1.x * C + c], a1);
      a2 = fmaf(__int_as_float(r2.y), H[(size_t)r2.x * C + c], a2);
      a3 = fmaf(__int_as_float(r3.y), H[(size_t)r3.x * C + c], a3);
    }
    for (; e < end; ++e) {
      int2 r = rec[e];
      a0 = fmaf(__int_as_float(r.y), H[(size_t)r.x * C + c], a0);
    }
    a0 += a1 + a2 + a3;
  } else {
    // C==32: half-waves split the edge list (stride 2), then shfl-combine.
    const int half = lane >> 5;
    a0 = half ? 0.f : H[(size_t)n * C + c] * (di * di);
    int e = beg + half;
    for (; e + 6 < end; e += 8) {
      int2 r0 = rec[e + 0];
      int2 r1 = rec[e + 2];
      int2 r2 = rec[e + 4];
      int2 r3 = rec[e + 6];
      a0 = fmaf(__int_as_float(r0.y), H[(size_t)r0.x * C + c], a0);
      a1 = fmaf(__int_as_float(r1.y), H[(size_t)r1.x * C + c], a1);
      a2 = fmaf(__int_as_float(r2.y), H[(size_t)r2.x * C + c], a2);
      a3 = fmaf(__int_as_float(r3.y), H[(size_t)r3.x * C + c], a3);
    }
    for (; e < end; e += 2) {
      int2 r = rec[e];
      a0 = fmaf(__int_as_float(r.y), H[(size_t)r.x * C + c], a0);
    }
    a0 += a1 + a2 + a3;
    a0 += __shfl_xor(a0, 32);  // combine half-wave partial sums
    if (half) return;          // lower half writes
  }
  a0 += bias[c];
  if (RELU) a0 = fmaxf(a0, 0.f);
  out[(size_t)n * C + c] = a0;
}

extern "C" void kernel_launch(void* const* d_in, const int* in_sizes, int n_in,
                              void* d_out, int out_size, void* d_ws, size_t ws_size,
                              hipStream_t stream) {
  (void)n_in; (void)out_size; (void)ws_size;
  const float* x = (const float*)d_in[0];
  const int* edges = (const int*)d_in[1];
  const float* W1 = (const float*)d_in[2];
  const float* b1 = (const float*)d_in[3];
  const float* W2 = (const float*)d_in[4];
  const float* b2 = (const float*)d_in[5];

  const int N = in_sizes[0] / 64;
  const int E = in_sizes[1] / 2;

  // workspace carve-up (256B aligned)
  char* ws = (char*)d_ws;
  size_t off = 0;
  auto carve = [&](size_t bytes) -> void* {
    void* p = ws + off;
    off = (off + bytes + 255) & ~(size_t)255;
    return p;
  };
  int* flag     = (int*)carve(4);
  int* cnt      = (int*)carve((size_t)N * 4);
  int* rowptr   = (int*)carve((size_t)(N + 1) * 4);
  int* cursor   = (int*)carve((size_t)N * 4);
  float* dinv   = (float*)carve((size_t)N * 4);
  int* partial  = (int*)carve(1024);
  int2* rec     = (int2*)carve((size_t)E * 8);
  float* h1     = (float*)carve((size_t)N * 64 * 4);
  float* g1     = (float*)carve((size_t)N * 64 * 4);
  float* h2     = (float*)carve((size_t)N * 32 * 4);

  const int nbN = (N + 255) / 256;
  const int nbE = (E + 255) / 256;
  const int NB = (N + 1023) / 1024;  // must be <= 256 (N <= 262144)

  k_init<<<nbN, 256, 0, stream>>>(cnt, N, flag);
  k_detect<<<4, 256, 0, stream>>>(edges, 2 * E, flag);
  k_hist<<<nbE, 256, 0, stream>>>(edges, E, cnt, flag);
  k_dinv<<<nbN, 256, 0, stream>>>(cnt, dinv, N);
  k_scan1<<<NB, 256, 0, stream>>>(cnt, N, rowptr, partial);
  k_scan2<<<1, 256, 0, stream>>>(partial, NB);
  k_scan3<<<nbN, 256, 0, stream>>>(rowptr, cursor, partial, N, E);
  k_fill<<<nbE, 256, 0, stream>>>(edges, E, dinv, cursor, rec, flag);

  k_gemm<64, 64><<<(N + 63) / 64, 256, 0, stream>>>(x, W1, h1, N);
  k_prop<64, true><<<(N + 3) / 4, 256, 0, stream>>>(h1, rec, rowptr, dinv, b1, g1, N);
  k_gemm<64, 32><<<(N + 63) / 64, 256, 0, stream>>>(g1, W2, h2, N);
  k_prop<32, false><<<(N + 3) / 4, 256, 0, stream>>>(h2, rec, rowptr, dinv, b2,
                                                     (float*)d_out, N);
}

// Round 3
// 336.203 us; speedup vs baseline: 1.9617x; 1.9617x over previous
//
#include <hip/hip_runtime.h>
#include <cstdint>
#include <cstddef>

// ---------------------------------------------------------------------------
// GCN 2-layer: out = GCNConv2( relu( GCNConv1(x) ) )
//   1. Build degree + CSR (grouped by dst) once per call; reused by both layers.
//   2. h1 = x @ W1            (LDS-W tile GEMM, 1 float4 per thread -> no spill)
//   3. g1 = relu(prop(h1)+b1) (pull-style gather, 4-way unrolled, no float atomics)
//   4. h2 = g1 @ W2
//   5. out = prop(h2) + b2
// Edge dtype (int32 vs int64) detected on-device via high words.
// ---------------------------------------------------------------------------

__global__ void k_init(int* __restrict__ cnt, int N, int* __restrict__ flag) {
  int i = blockIdx.x * blockDim.x + threadIdx.x;
  if (i < N) cnt[i] = 0;
  if (i == 0) *flag = 1;  // assume int64 until proven otherwise
}

__global__ void k_detect(const int* __restrict__ e32, int twoE, int* __restrict__ flag) {
  int i = blockIdx.x * blockDim.x + threadIdx.x;
  if (i < 1024) {
    int idx = 2 * i + 1;  // odd int32 slots = high words if buffer is int64
    if (idx < twoE && e32[idx] != 0) atomicAnd(flag, 0);  // int32 data
  }
}

__device__ __forceinline__ int load_edge(const int* e32, int idx, int is64) {
  if (is64) return (int)((const long long*)e32)[idx];
  return e32[idx];
}

__global__ void k_hist(const int* __restrict__ e32, int E, int* __restrict__ cnt,
                       const int* __restrict__ flag) {
  int i = blockIdx.x * blockDim.x + threadIdx.x;
  if (i >= E) return;
  int is64 = *flag;
  int d = load_edge(e32, E + i, is64);
  atomicAdd(&cnt[d], 1);
}

__global__ void k_dinv(const int* __restrict__ cnt, float* __restrict__ dinv, int N) {
  int i = blockIdx.x * blockDim.x + threadIdx.x;
  if (i < N) dinv[i] = rsqrtf((float)cnt[i] + 1.0f);  // +1 = self-loop
}

// ---- exclusive scan of cnt -> rowptr (3-pass, 1024 elems/block) ----
__global__ void k_scan1(const int* __restrict__ cnt, int N, int* __restrict__ rowptr,
                        int* __restrict__ partial) {
  __shared__ int sh[256];
  const int t = threadIdx.x;
  const int base = blockIdx.x * 1024 + t * 4;
  int v0 = (base + 0 < N) ? cnt[base + 0] : 0;
  int v1 = (base + 1 < N) ? cnt[base + 1] : 0;
  int v2 = (base + 2 < N) ? cnt[base + 2] : 0;
  int v3 = (base + 3 < N) ? cnt[base + 3] : 0;
  int s = v0 + v1 + v2 + v3;
  sh[t] = s;
  __syncthreads();
  for (int off = 1; off < 256; off <<= 1) {
    int add = (t >= off) ? sh[t - off] : 0;
    __syncthreads();
    sh[t] += add;
    __syncthreads();
  }
  int excl = sh[t] - s;
  if (base + 0 < N) rowptr[base + 0] = excl;
  if (base + 1 < N) rowptr[base + 1] = excl + v0;
  if (base + 2 < N) rowptr[base + 2] = excl + v0 + v1;
  if (base + 3 < N) rowptr[base + 3] = excl + v0 + v1 + v2;
  if (t == 255) partial[blockIdx.x] = sh[255];
}

__global__ void k_scan2(int* __restrict__ partial, int NB) {
  __shared__ int sh[256];
  int t = threadIdx.x;
  int v = (t < NB) ? partial[t] : 0;
  sh[t] = v;
  __syncthreads();
  for (int off = 1; off < 256; off <<= 1) {
    int add = (t >= off) ? sh[t - off] : 0;
    __syncthreads();
    sh[t] += add;
    __syncthreads();
  }
  if (t < NB) partial[t] = sh[t] - v;  // exclusive
}

__global__ void k_scan3(int* __restrict__ rowptr, int* __restrict__ cursor,
                        const int* __restrict__ partial, int N, int E) {
  int i = blockIdx.x * blockDim.x + threadIdx.x;
  if (i < N) {
    int r = rowptr[i] + partial[i >> 10];
    rowptr[i] = r;
    cursor[i] = r;
  }
  if (i == 0) rowptr[N] = E;
}

__global__ void k_fill(const int* __restrict__ e32, int E, const float* __restrict__ dinv,
                       int* __restrict__ cursor, int2* __restrict__ rec,
                       const int* __restrict__ flag) {
  int i = blockIdx.x * blockDim.x + threadIdx.x;
  if (i >= E) return;
  int is64 = *flag;
  int s = load_edge(e32, i, is64);
  int d = load_edge(e32, E + i, is64);
  int pos = atomicAdd(&cursor[d], 1);
  float w = dinv[s] * dinv[d];
  rec[pos] = make_int2(s, __float_as_int(w));
}

// ---- dense transform H[N][COUT] = X[N][CIN] @ W[CIN][COUT] ----
// Block = 256 threads = NODES x Q (Q = COUT/4 float4-quads per row).
// W fully staged in LDS; X tile staged padded (stride CIN+1) to avoid bank
// conflicts on the node-broadcast read. Each thread owns ONE output float4:
// ~25 live VGPRs, structurally no spill.
template <int CIN, int COUT>
__global__ void k_gemm(const float* __restrict__ X, const float* __restrict__ W,
                       float* __restrict__ H, int N) {
  constexpr int Q = COUT / 4;       // 16 (layer1) or 8 (layer2)
  constexpr int NODES = 256 / Q;    // 16 or 32
  __shared__ float4 Ws[CIN * Q];            // full W: 16 KB / 8 KB
  __shared__ float Xs[NODES][CIN + 1];      // padded: stride 65 floats
  const int t = threadIdx.x;
  const int nodebase = blockIdx.x * NODES;

  // stage W (coalesced float4)
  const float4* W4 = (const float4*)W;
#pragma unroll
  for (int i = t; i < CIN * Q; i += 256) Ws[i] = W4[i];

  // stage X tile: float4 global read, scalar LDS writes into padded rows
  const float4* X4 = (const float4*)X;
#pragma unroll
  for (int i = t; i < NODES * (CIN / 4); i += 256) {
    int r = i / (CIN / 4);
    int k4 = i % (CIN / 4);
    int gr = nodebase + r;
    if (gr > N - 1) gr = N - 1;  // tail clamp (dup reads, harmless)
    float4 v = X4[(size_t)gr * (CIN / 4) + k4];
    Xs[r][k4 * 4 + 0] = v.x;
    Xs[r][k4 * 4 + 1] = v.y;
    Xs[r][k4 * 4 + 2] = v.z;
    Xs[r][k4 * 4 + 3] = v.w;
  }
  __syncthreads();

  const int q = t % Q;        // output quad
  const int nl = t / Q;       // local node
  float4 acc = make_float4(0.f, 0.f, 0.f, 0.f);
#pragma unroll 4
  for (int k = 0; k < CIN; ++k) {
    float xv = Xs[nl][k];
    float4 wv = Ws[k * Q + q];
    acc.x = fmaf(xv, wv.x, acc.x);
    acc.y = fmaf(xv, wv.y, acc.y);
    acc.z = fmaf(xv, wv.z, acc.z);
    acc.w = fmaf(xv, wv.w, acc.w);
  }
  const int n = nodebase + nl;
  if (n < N) ((float4*)H)[(size_t)n * Q + q] = acc;
}

// ---- pull-style propagation: one wave per destination node ----
// 4-way unrolled edge loop: 4 independent accumulators -> 4 row-gathers
// (1 KB) in flight per wave, breaking the fmaf dependency chain.
template <int C, bool RELU>
__global__ void k_prop(const float* __restrict__ H, const int2* __restrict__ rec,
                       const int* __restrict__ rowptr, const float* __restrict__ dinv,
                       const float* __restrict__ bias, float* __restrict__ out, int N) {
  const int gid = blockIdx.x * blockDim.x + threadIdx.x;
  const int n = gid >> 6;
  const int lane = threadIdx.x & 63;
  if (n >= N) return;
  const int c = lane & (C - 1);
  const float di = dinv[n];
  const int beg = rowptr[n];
  const int end = rowptr[n + 1];
  float a0, a1 = 0.f, a2 = 0.f, a3 = 0.f;
  if (C == 64) {
    a0 = H[(size_t)n * C + c] * (di * di);  // self-loop term
    int e = beg;
    for (; e + 4 <= end; e += 4) {
      int2 r0 = rec[e + 0];
      int2 r1 = rec[e + 1];
      int2 r2 = rec[e + 2];
      int2 r3 = rec[e + 3];
      a0 = fmaf(__int_as_float(r0.y), H[(size_t)r0.x * C + c], a0);
      a1 = fmaf(__int_as_float(r1.y), H[(size_t)r1.x * C + c], a1);
      a2 = fmaf(__int_as_float(r2.y), H[(size_t)r2.x * C + c], a2);
      a3 = fmaf(__int_as_float(r3.y), H[(size_t)r3.x * C + c], a3);
    }
    for (; e < end; ++e) {
      int2 r = rec[e];
      a0 = fmaf(__int_as_float(r.y), H[(size_t)r.x * C + c], a0);
    }
    a0 += a1 + a2 + a3;
  } else {
    // C==32: half-waves split the edge list (stride 2), then shfl-combine.
    const int half = lane >> 5;
    a0 = half ? 0.f : H[(size_t)n * C + c] * (di * di);
    int e = beg + half;
    for (; e + 6 < end; e += 8) {
      int2 r0 = rec[e + 0];
      int2 r1 = rec[e + 2];
      int2 r2 = rec[e + 4];
      int2 r3 = rec[e + 6];
      a0 = fmaf(__int_as_float(r0.y), H[(size_t)r0.x * C + c], a0);
      a1 = fmaf(__int_as_float(r1.y), H[(size_t)r1.x * C + c], a1);
      a2 = fmaf(__int_as_float(r2.y), H[(size_t)r2.x * C + c], a2);
      a3 = fmaf(__int_as_float(r3.y), H[(size_t)r3.x * C + c], a3);
    }
    for (; e < end; e += 2) {
      int2 r = rec[e];
      a0 = fmaf(__int_as_float(r.y), H[(size_t)r.x * C + c], a0);
    }
    a0 += a1 + a2 + a3;
    a0 += __shfl_xor(a0, 32);  // combine half-wave partial sums
    if (half) return;          // lower half writes
  }
  a0 += bias[c];
  if (RELU) a0 = fmaxf(a0, 0.f);
  out[(size_t)n * C + c] = a0;
}

extern "C" void kernel_launch(void* const* d_in, const int* in_sizes, int n_in,
                              void* d_out, int out_size, void* d_ws, size_t ws_size,
                              hipStream_t stream) {
  (void)n_in; (void)out_size; (void)ws_size;
  const float* x = (const float*)d_in[0];
  const int* edges = (const int*)d_in[1];
  const float* W1 = (const float*)d_in[2];
  const float* b1 = (const float*)d_in[3];
  const float* W2 = (const float*)d_in[4];
  const float* b2 = (const float*)d_in[5];

  const int N = in_sizes[0] / 64;
  const int E = in_sizes[1] / 2;

  // workspace carve-up (256B aligned)
  char* ws = (char*)d_ws;
  size_t off = 0;
  auto carve = [&](size_t bytes) -> void* {
    void* p = ws + off;
    off = (off + bytes + 255) & ~(size_t)255;
    return p;
  };
  int* flag     = (int*)carve(4);
  int* cnt      = (int*)carve((size_t)N * 4);
  int* rowptr   = (int*)carve((size_t)(N + 1) * 4);
  int* cursor   = (int*)carve((size_t)N * 4);
  float* dinv   = (float*)carve((size_t)N * 4);
  int* partial  = (int*)carve(1024);
  int2* rec     = (int2*)carve((size_t)E * 8);
  float* h1     = (float*)carve((size_t)N * 64 * 4);
  float* g1     = (float*)carve((size_t)N * 64 * 4);
  float* h2     = (float*)carve((size_t)N * 32 * 4);

  const int nbN = (N + 255) / 256;
  const int nbE = (E + 255) / 256;
  const int NB = (N + 1023) / 1024;  // must be <= 256 (N <= 262144)

  k_init<<<nbN, 256, 0, stream>>>(cnt, N, flag);
  k_detect<<<4, 256, 0, stream>>>(edges, 2 * E, flag);
  k_hist<<<nbE, 256, 0, stream>>>(edges, E, cnt, flag);
  k_dinv<<<nbN, 256, 0, stream>>>(cnt, dinv, N);
  k_scan1<<<NB, 256, 0, stream>>>(cnt, N, rowptr, partial);
  k_scan2<<<1, 256, 0, stream>>>(partial, NB);
  k_scan3<<<nbN, 256, 0, stream>>>(rowptr, cursor, partial, N, E);
  k_fill<<<nbE, 256, 0, stream>>>(edges, E, dinv, cursor, rec, flag);

  k_gemm<64, 64><<<(N + 15) / 16, 256, 0, stream>>>(x, W1, h1, N);
  k_prop<64, true><<<(N + 3) / 4, 256, 0, stream>>>(h1, rec, rowptr, dinv, b1, g1, N);
  k_gemm<64, 32><<<(N + 31) / 32, 256, 0, stream>>>(g1, W2, h2, N);
  k_prop<32, false><<<(N + 3) / 4, 256, 0, stream>>>(h2, rec, rowptr, dinv, b2,
                                                     (float*)d_out, N);
}